// Round 7
// baseline (168.090 us; speedup 1.0000x reference)
//
#include <hip/hip_runtime.h>
#include <hip/hip_bf16.h>
#include <stdint.h>

// Flash attention B=4,H=8,S=2048,D=64 fp32 io, bf16 MFMA compute.
// Round 7: barrier-free main loop. Prepass bakes fragment-major K/V images;
// waves load MFMA fragments directly from global (L1/L2-resident), no LDS,
// no __syncthreads. Softmax numerics verbatim R6 (verified).

typedef __bf16 bf16;
typedef __attribute__((ext_vector_type(8))) __bf16 bf16x8;
typedef __attribute__((ext_vector_type(4))) __bf16 bf16x4;
typedef __attribute__((ext_vector_type(4))) float floatx4;

#define SLEN 2048
#define DH   64
#define BR   64
#define BC   64
#define NKT  (SLEN / BC)
#define NQT  (SLEN / BR)
#define BH_N 32
#define LOG2E 1.44269504088896341f

#define IMGE_G 4096            // bf16 elements per image per tile (8192 B)

static_assert(BH_N == NQT, "prep kernel folds bh and qt onto one grid axis");

// logical key l (0..63) -> physical key within tile (PV A-fragment order)
static __device__ inline int phys_key(int l) {
    int h = l >> 5, l5 = l & 31, q = l5 >> 3, j = l5 & 7;
    return 32 * h + (j < 4 ? 4 * q + j : 16 + 4 * q + (j - 4));
}

// ---- prepass: kv -> fragment-major bf16 K/V images + mask tile flags ----
// K image: granule G in [0,512): j=G>>6 (fragment = (nt=j>>1, kc=j&1)),
//   lane=G&63 -> content K[key=16*(j>>1)+(lane&15)][d=(j&1)*32+(lane>>4)*8 ..+8]
// V image: j2=G>>6 (fragment = (dt=j2>>1, kc=j2&1)), lane=G&63 ->
//   content V^T[d=16*(j2>>1)+(lane&15)][logical keys (j2&1)*32+(lane>>4)*8 ..+8]
__global__ __launch_bounds__(256) void kv_prep(
    const float* __restrict__ kv, const float* __restrict__ mask,
    bf16* __restrict__ kvK, bf16* __restrict__ kvT, int* __restrict__ flags)
{
    __shared__ bf16 Tl[64 * 72];
    __shared__ int wany[4];
    const int kt = blockIdx.x, z = blockIdx.y;   // z = bh for kv, z = qt for mask
    const int t = threadIdx.x;

    // mask flag part (z = qt)
    float acc = 0.f;
#pragma unroll
    for (int i = 0; i < 4; ++i) {
        int f = i * 256 + t;
        int row = f >> 4, c4 = (f & 15) * 4;
        const float4 v = *(const float4*)(mask + (size_t)(z * BR + row) * SLEN + kt * BC + c4);
        acc = fmaxf(acc, fmaxf(fmaxf(fabsf(v.x), fabsf(v.y)), fmaxf(fabsf(v.z), fabsf(v.w))));
    }
    unsigned long long any = __ballot(acc != 0.f);
    if ((t & 63) == 0) wany[t >> 6] = (any != 0ull) ? 1 : 0;

    // kv tile load (z = bh): 64 keys x 64 d fp32 -> bf16 Tl[key][d]
    const float* src = kv + ((size_t)z * SLEN + kt * BC) * DH;
#pragma unroll
    for (int i = 0; i < 4; ++i) {
        int f = i * 256 + t;
        int key = f >> 4, d4 = (f & 15) * 4;
        float4 v = *(const float4*)(src + (size_t)key * DH + d4);
        bf16x4 b; b[0] = (bf16)v.x; b[1] = (bf16)v.y; b[2] = (bf16)v.z; b[3] = (bf16)v.w;
        *(bf16x4*)&Tl[key * 72 + d4] = b;
    }
    __syncthreads();
    if (t == 0) flags[z * NKT + kt] = wany[0] | wany[1] | wany[2] | wany[3];

    // K image (fragment-major)
    bf16* outK = kvK + ((size_t)z * NKT + kt) * IMGE_G;
#pragma unroll
    for (int i = 0; i < 2; ++i) {
        int G = i * 256 + t;
        int j = G >> 6, ln = G & 63;
        int row = 16 * (j >> 1) + (ln & 15);
        int d0 = (j & 1) * 32 + ((ln >> 4) << 3);
        bf16x8 w = *(const bf16x8*)&Tl[row * 72 + d0];
        *(bf16x8*)(outK + (size_t)G * 8) = w;
    }
    // V image (fragment-major, logical-key gather)
    bf16* outV = kvT + ((size_t)z * NKT + kt) * IMGE_G;
#pragma unroll
    for (int i = 0; i < 2; ++i) {
        int G = i * 256 + t;
        int j = G >> 6, ln = G & 63;
        int d = 16 * (j >> 1) + (ln & 15);
        int l0 = (j & 1) * 32 + ((ln >> 4) << 3);
        bf16x8 w;
#pragma unroll
        for (int jj = 0; jj < 8; ++jj)
            w[jj] = Tl[phys_key(l0 + jj) * 72 + d];
        *(bf16x8*)(outV + (size_t)G * 8) = w;
    }
}

// ---- main fused attention: barrier-free, direct-global fragments ----
__global__ __launch_bounds__(256) void attn_fwd7(
    const float* __restrict__ q, const float* __restrict__ mask,
    const int* __restrict__ flags,
    const bf16* __restrict__ kvK, const bf16* __restrict__ kvT,
    float* __restrict__ out)
{
    const int bh = blockIdx.x;      // bh fast: all qt-blocks of a bh share an XCD L2
    const int qt = blockIdx.y;
    const int q0 = qt * BR;
    const int t = threadIdx.x;
    const int wave = t >> 6, lane = t & 63;
    const int ln16 = lane & 15, quad = lane >> 4;

    // Q B-fragments (scale folded): B[k=kc*32+quad*8+j][n=qrow=ln16]  (R6 verbatim)
    const float qscale = 0.125f * LOG2E;
    bf16x8 aq[2];
    {
        const float* qrow = q + ((size_t)bh * SLEN + q0 + wave * 16 + ln16) * DH;
#pragma unroll
        for (int kc = 0; kc < 2; ++kc) {
            float4 f0 = *(const float4*)(qrow + kc * 32 + quad * 8);
            float4 f1 = *(const float4*)(qrow + kc * 32 + quad * 8 + 4);
            bf16x8 a;
            a[0] = (bf16)(f0.x * qscale); a[1] = (bf16)(f0.y * qscale);
            a[2] = (bf16)(f0.z * qscale); a[3] = (bf16)(f0.w * qscale);
            a[4] = (bf16)(f1.x * qscale); a[5] = (bf16)(f1.y * qscale);
            a[6] = (bf16)(f1.z * qscale); a[7] = (bf16)(f1.w * qscale);
            aq[kc] = a;
        }
    }

    // flag bitmask for this qt (bit kt)
    unsigned fmask;
    {
        int ld = (lane < 32) ? flags[qt * NKT + lane] : 0;
        fmask = (unsigned)__ballot(ld != 0);
    }

    floatx4 o[4];
#pragma unroll
    for (int dt = 0; dt < 4; ++dt) o[dt] = (floatx4){0.f, 0.f, 0.f, 0.f};
    float m_run = -3.0e38f, l_run = 0.f;

    const bf16* Kb = kvK + (size_t)bh * NKT * IMGE_G;
    const bf16* Vb = kvT + (size_t)bh * NKT * IMGE_G;
    const int fo = lane * 8;   // element offset of this lane's 16B chunk

    // prologue: K fragments of tile 0
    bf16x8 kf[8];
#pragma unroll
    for (int j = 0; j < 8; ++j) kf[j] = *(const bf16x8*)(Kb + j * 512 + fo);

    for (int kt = 0; kt < NKT; ++kt) {
        // V fragments for this tile (issued ~QK+softmax ahead of use)
        const bf16* Vt = Vb + (size_t)kt * IMGE_G;
        bf16x8 vf[8];
#pragma unroll
        for (int j = 0; j < 8; ++j) vf[j] = *(const bf16x8*)(Vt + j * 512 + fo);

        // S^T = K * Q^T : D[m=phys key][n=qrow]
        floatx4 s[4];
#pragma unroll
        for (int nt = 0; nt < 4; ++nt) {
            floatx4 acc = (floatx4){0.f, 0.f, 0.f, 0.f};
            acc = __builtin_amdgcn_mfma_f32_16x16x32_bf16(kf[2 * nt],     aq[0], acc, 0, 0, 0);
            acc = __builtin_amdgcn_mfma_f32_16x16x32_bf16(kf[2 * nt + 1], aq[1], acc, 0, 0, 0);
            s[nt] = acc;
        }

        // in-place prefetch of next tile's K fragments (clamped; free-running)
        {
            int ktn = (kt + 1 < NKT) ? kt + 1 : kt;
            const bf16* Kn = Kb + (size_t)ktn * IMGE_G;
#pragma unroll
            for (int j = 0; j < 8; ++j) kf[j] = *(const bf16x8*)(Kn + j * 512 + fo);
        }

        // mask add (phys key = 16nt+quad*4+r, qrow = ln16); usually skipped
        if (fmask & (1u << kt)) {
            const float* mrow = mask + (size_t)(q0 + wave * 16 + ln16) * SLEN + kt * BC;
#pragma unroll
            for (int nt = 0; nt < 4; ++nt) {
                float4 mv = *(const float4*)(mrow + 16 * nt + quad * 4);
                s[nt][0] += mv.x * LOG2E; s[nt][1] += mv.y * LOG2E;
                s[nt][2] += mv.z * LOG2E; s[nt][3] += mv.w * LOG2E;
            }
        }

        // online softmax (R6 verbatim): one q-row per lane (row = ln16)
        float t01 = fmaxf(fmaxf(s[0][0], s[0][1]), fmaxf(s[0][2], s[0][3]));
        float t23 = fmaxf(fmaxf(s[1][0], s[1][1]), fmaxf(s[1][2], s[1][3]));
        float t45 = fmaxf(fmaxf(s[2][0], s[2][1]), fmaxf(s[2][2], s[2][3]));
        float t67 = fmaxf(fmaxf(s[3][0], s[3][1]), fmaxf(s[3][2], s[3][3]));
        float tmax = fmaxf(fmaxf(t01, t23), fmaxf(t45, t67));
        tmax = fmaxf(tmax, __shfl_xor(tmax, 16));
        tmax = fmaxf(tmax, __shfl_xor(tmax, 32));
        float mnew = fmaxf(m_run, tmax);
        unsigned long long grew = __ballot(mnew > m_run);
        float alpha = exp2f(m_run - mnew);
        m_run = mnew;

        float rs = 0.f;
        bf16x8 pf0, pf1;
#pragma unroll
        for (int r = 0; r < 4; ++r) {
            float p0 = exp2f(s[0][r] - mnew);
            float p1 = exp2f(s[1][r] - mnew);
            float p2 = exp2f(s[2][r] - mnew);
            float p3 = exp2f(s[3][r] - mnew);
            rs += (p0 + p1) + (p2 + p3);
            pf0[r] = (bf16)p0; pf0[4 + r] = (bf16)p1;
            pf1[r] = (bf16)p2; pf1[4 + r] = (bf16)p3;
        }
        rs += __shfl_xor(rs, 16);
        rs += __shfl_xor(rs, 32);

        if (grew) {
            l_run = l_run * alpha + rs;
            float a0 = __shfl(alpha, quad * 4 + 0);
            float a1 = __shfl(alpha, quad * 4 + 1);
            float a2 = __shfl(alpha, quad * 4 + 2);
            float a3 = __shfl(alpha, quad * 4 + 3);
#pragma unroll
            for (int dt = 0; dt < 4; ++dt) {
                o[dt][0] *= a0; o[dt][1] *= a1; o[dt][2] *= a2; o[dt][3] *= a3;
            }
        } else {
            l_run += rs;
        }

        // O += P V : A = pf (logical key order), B = vf fragments
#pragma unroll
        for (int dt = 0; dt < 4; ++dt) {
            o[dt] = __builtin_amdgcn_mfma_f32_16x16x32_bf16(pf0, vf[2 * dt],     o[dt], 0, 0, 0);
            o[dt] = __builtin_amdgcn_mfma_f32_16x16x32_bf16(pf1, vf[2 * dt + 1], o[dt], 0, 0, 0);
        }
    }

    // epilogue (R6 verbatim): O rows = quad*4+r, cols = ln16+16dt
    float l0 = __shfl(l_run, quad * 4 + 0);
    float l1 = __shfl(l_run, quad * 4 + 1);
    float l2 = __shfl(l_run, quad * 4 + 2);
    float l3 = __shfl(l_run, quad * 4 + 3);
    float i0 = 1.f / l0, i1 = 1.f / l1, i2 = 1.f / l2, i3 = 1.f / l3;
    float* ob = out + ((size_t)bh * SLEN + q0 + wave * 16) * DH;
#pragma unroll
    for (int dt = 0; dt < 4; ++dt) {
        int col = ln16 + 16 * dt;
        ob[(quad * 4 + 0) * DH + col] = o[dt][0] * i0;
        ob[(quad * 4 + 1) * DH + col] = o[dt][1] * i1;
        ob[(quad * 4 + 2) * DH + col] = o[dt][2] * i2;
        ob[(quad * 4 + 3) * DH + col] = o[dt][3] * i3;
    }
}

// ---- legacy fallback (round-1 kernel) if ws is too small for the prepass ----
#define LDT 72
__global__ __launch_bounds__(256) void attn_mask_flags(
    const float* __restrict__ mask, int* __restrict__ flags)
{
    const int kt = blockIdx.x, qt = blockIdx.y;
    const int t = threadIdx.x;
    float acc = 0.f;
#pragma unroll
    for (int i = 0; i < 4; ++i) {
        int f = i * 256 + t;
        int row = f >> 4, c4 = (f & 15) * 4;
        const float4 v = *(const float4*)(mask + (size_t)(qt * BR + row) * SLEN + kt * BC + c4);
        acc = fmaxf(acc, fmaxf(fmaxf(fabsf(v.x), fabsf(v.y)), fmaxf(fabsf(v.z), fabsf(v.w))));
    }
    unsigned long long any = __ballot(acc != 0.f);
    __shared__ int wany[4];
    if ((t & 63) == 0) wany[t >> 6] = (any != 0ull) ? 1 : 0;
    __syncthreads();
    if (t == 0) flags[qt * NKT + kt] = wany[0] | wany[1] | wany[2] | wany[3];
}

__global__ __launch_bounds__(256) void attn_fwd(
    const float* __restrict__ q, const float* __restrict__ kv,
    const float* __restrict__ mask, const int* __restrict__ flags,
    float* __restrict__ out)
{
    __shared__ __align__(16) bf16 Kl[BC * LDT];
    __shared__ __align__(16) bf16 Vt[DH * LDT];
    __shared__ __align__(16) bf16 Pl[BR * LDT];

    const int qt = blockIdx.x;
    const int bh = blockIdx.y;
    const int q0 = qt * BR;
    const int t = threadIdx.x;
    const int wave = t >> 6, lane = t & 63;
    const int ln16 = lane & 15, quad = lane >> 4;

    const float qscale = 0.125f * LOG2E;
    bf16x8 aq[2];
    {
        const float* qrow = q + ((size_t)bh * SLEN + q0 + wave * 16 + ln16) * DH;
#pragma unroll
        for (int kc = 0; kc < 2; ++kc) {
            float4 f0 = *(const float4*)(qrow + kc * 32 + quad * 8);
            float4 f1 = *(const float4*)(qrow + kc * 32 + quad * 8 + 4);
            bf16x8 a;
            a[0] = (bf16)(f0.x * qscale); a[1] = (bf16)(f0.y * qscale);
            a[2] = (bf16)(f0.z * qscale); a[3] = (bf16)(f0.w * qscale);
            a[4] = (bf16)(f1.x * qscale); a[5] = (bf16)(f1.y * qscale);
            a[6] = (bf16)(f1.z * qscale); a[7] = (bf16)(f1.w * qscale);
            aq[kc] = a;
        }
    }

    floatx4 o[4];
#pragma unroll
    for (int dt = 0; dt < 4; ++dt) o[dt] = (floatx4){0.f, 0.f, 0.f, 0.f};
    float m_run[4], l_run[4];
#pragma unroll
    for (int r = 0; r < 4; ++r) { m_run[r] = -3.0e38f; l_run[r] = 0.f; }

    const float* kvb = kv + (size_t)bh * SLEN * DH;

    for (int kt = 0; kt < NKT; ++kt) {
        float4 st[4];
        const float* kvt = kvb + (size_t)kt * BC * DH;
#pragma unroll
        for (int i = 0; i < 4; ++i) {
            int f = i * 256 + t;
            st[i] = *(const float4*)(kvt + (size_t)f * 4);
        }
        __syncthreads();
#pragma unroll
        for (int i = 0; i < 4; ++i) {
            int f = i * 256 + t;
            int key = f >> 4, d4 = (f & 15) * 4;
            bf16 b0 = (bf16)st[i].x, b1 = (bf16)st[i].y, b2 = (bf16)st[i].z, b3 = (bf16)st[i].w;
            *(bf16x4*)&Kl[key * LDT + d4] = (bf16x4){b0, b1, b2, b3};
            Vt[(d4 + 0) * LDT + key] = b0;
            Vt[(d4 + 1) * LDT + key] = b1;
            Vt[(d4 + 2) * LDT + key] = b2;
            Vt[(d4 + 3) * LDT + key] = b3;
        }
        __syncthreads();

        floatx4 s[4];
#pragma unroll
        for (int nt = 0; nt < 4; ++nt) {
            s[nt] = (floatx4){0.f, 0.f, 0.f, 0.f};
#pragma unroll
            for (int kc = 0; kc < 2; ++kc) {
                bf16x8 bk = *(const bf16x8*)&Kl[(ln16 + 16 * nt) * LDT + kc * 32 + quad * 8];
                s[nt] = __builtin_amdgcn_mfma_f32_16x16x32_bf16(aq[kc], bk, s[nt], 0, 0, 0);
            }
        }

        if (!flags || flags[qt * NKT + kt]) {
            const float* mrow = mask + (size_t)(q0 + quad * 4) * SLEN + kt * BC + ln16;
#pragma unroll
            for (int r = 0; r < 4; ++r)
#pragma unroll
                for (int nt = 0; nt < 4; ++nt)
                    s[nt][r] += mrow[(size_t)r * SLEN + nt * 16] * LOG2E;
        }

#pragma unroll
        for (int r = 0; r < 4; ++r) {
            float mx = fmaxf(fmaxf(s[0][r], s[1][r]), fmaxf(s[2][r], s[3][r]));
            mx = fmaxf(mx, __shfl_xor(mx, 1));
            mx = fmaxf(mx, __shfl_xor(mx, 2));
            mx = fmaxf(mx, __shfl_xor(mx, 4));
            mx = fmaxf(mx, __shfl_xor(mx, 8));
            float mnew = fmaxf(m_run[r], mx);
            float alpha = exp2f(m_run[r] - mnew);
            m_run[r] = mnew;
            float rs = 0.f;
#pragma unroll
            for (int nt = 0; nt < 4; ++nt) {
                float p = exp2f(s[nt][r] - mnew);
                s[nt][r] = p;
                rs += p;
            }
            rs += __shfl_xor(rs, 1);
            rs += __shfl_xor(rs, 2);
            rs += __shfl_xor(rs, 4);
            rs += __shfl_xor(rs, 8);
            l_run[r] = l_run[r] * alpha + rs;
#pragma unroll
            for (int dt = 0; dt < 4; ++dt) o[dt][r] *= alpha;
        }

#pragma unroll
        for (int nt = 0; nt < 4; ++nt)
#pragma unroll
            for (int r = 0; r < 4; ++r)
                Pl[(wave * 16 + quad * 4 + r) * LDT + ln16 + 16 * nt] = (bf16)s[nt][r];

#pragma unroll
        for (int kc2 = 0; kc2 < 2; ++kc2) {
            bf16x8 pfr = *(const bf16x8*)&Pl[(wave * 16 + ln16) * LDT + kc2 * 32 + quad * 8];
#pragma unroll
            for (int dt = 0; dt < 4; ++dt) {
                bf16x8 vfr = *(const bf16x8*)&Vt[(ln16 + 16 * dt) * LDT + kc2 * 32 + quad * 8];
                o[dt] = __builtin_amdgcn_mfma_f32_16x16x32_bf16(pfr, vfr, o[dt], 0, 0, 0);
            }
        }
    }

#pragma unroll
    for (int r = 0; r < 4; ++r) {
        float inv = 1.0f / l_run[r];
        int qrow = q0 + wave * 16 + quad * 4 + r;
        float* orow = out + ((size_t)bh * SLEN + qrow) * DH;
#pragma unroll
        for (int dt = 0; dt < 4; ++dt)
            orow[ln16 + 16 * dt] = o[dt][r] * inv;
    }
}

extern "C" void kernel_launch(void* const* d_in, const int* in_sizes, int n_in,
                              void* d_out, int out_size, void* d_ws, size_t ws_size,
                              hipStream_t stream)
{
    const float* q    = (const float*)d_in[0];
    const float* kv   = (const float*)d_in[1];
    const float* mask = (const float*)d_in[2];
    float* out = (float*)d_out;

    const size_t kvKoff = 4096;                                   // flags: 32*32*4
    const size_t kvToff = kvKoff + (size_t)BH_N * NKT * IMGE_G * 2;
    const size_t need   = kvToff + (size_t)BH_N * NKT * IMGE_G * 2;

    if (ws_size >= need) {
        int*  flags = (int*)d_ws;
        bf16* kvK   = (bf16*)((char*)d_ws + kvKoff);
        bf16* kvT   = (bf16*)((char*)d_ws + kvToff);
        kv_prep<<<dim3(NKT, BH_N), 256, 0, stream>>>(kv, mask, kvK, kvT, flags);
        attn_fwd7<<<dim3(BH_N, NQT), 256, 0, stream>>>(q, mask, flags, kvK, kvT, out);
    } else {
        int* flags = nullptr;
        if (ws_size >= (size_t)NQT * NKT * sizeof(int)) {
            flags = (int*)d_ws;
            attn_mask_flags<<<dim3(NKT, NQT), 256, 0, stream>>>(mask, flags);
        }
        attn_fwd<<<dim3(NQT, BH_N), 256, 0, stream>>>(q, kv, mask, flags, out);
    }
}

// Round 8
// 154.794 us; speedup vs baseline: 1.0859x; 1.0859x over previous
//
#include <hip/hip_runtime.h>
#include <hip/hip_bf16.h>
#include <stdint.h>

// Flash attention B=4,H=8,S=2048,D=64 fp32 io, bf16 MFMA compute.
// Round 8: R6-verified structure, BC=128 keys per barrier epoch (16 epochs,
// half the serial softmax chains, 2 independent QK streams). Chunk stride
// 1024 (fits 64KB LDS double-buffered); bank-spread rotation g=(p-row-4*(c&1))&7
// baked in prepass preserves the R6 conflict-free read pattern.

typedef __bf16 bf16;
typedef __attribute__((ext_vector_type(8))) __bf16 bf16x8;
typedef __attribute__((ext_vector_type(4))) __bf16 bf16x4;
typedef __attribute__((ext_vector_type(4))) float floatx4;

#define SLEN 2048
#define DH   64
#define BR   64
#define BC   64
#define NKT  (SLEN / BC)      // 32 64-key tiles
#define NEP  (NKT / 2)        // 16 epochs of 128 keys
#define NQT  (SLEN / BR)
#define BH_N 32
#define LOG2E 1.44269504088896341f

#define CHB_L  1024           // LDS chunk stride (8 rows x 128B, no pad)
#define IMGB_L 8192           // bytes per K or V image (8 chunks)
#define IMGE_G 4096           // bf16 elements per image in global (8192 B)
#define BUF2   (4 * IMGB_L)   // K0,V0,K1,V1 per epoch buffer (32 KB)

#define AS1 __attribute__((address_space(1)))
#define AS3 __attribute__((address_space(3)))

static __device__ inline void gload_lds16(const void* g, void* l) {
    __builtin_amdgcn_global_load_lds((const AS1 uint32_t*)g, (AS3 uint32_t*)l, 16, 0, 0);
}

static_assert(BH_N == NQT, "prep kernel folds bh and qt onto one grid axis");

// logical key l (0..63) -> physical key within 64-key tile
static __device__ inline int phys_key(int l) {
    int h = l >> 5, l5 = l & 31, q = l5 >> 3, j = l5 & 7;
    return 32 * h + (j < 4 ? 4 * q + j : 16 + 4 * q + (j - 4));
}

// ---- prepass: kv -> swizzled bf16 K/V LDS-images + mask tile flags ----
// granule (chunk c, pos p, row rl): content granule g = (p - rl - 4*(c&1)) & 7
__global__ __launch_bounds__(256) void kv_prep(
    const float* __restrict__ kv, const float* __restrict__ mask,
    bf16* __restrict__ kvK, bf16* __restrict__ kvT, int* __restrict__ flags)
{
    __shared__ bf16 Tl[64 * 72];
    __shared__ int wany[4];
    const int kt = blockIdx.x, z = blockIdx.y;   // z = bh for kv, z = qt for mask
    const int t = threadIdx.x;

    // mask flag part (z = qt)
    float acc = 0.f;
#pragma unroll
    for (int i = 0; i < 4; ++i) {
        int f = i * 256 + t;
        int row = f >> 4, c4 = (f & 15) * 4;
        const float4 v = *(const float4*)(mask + (size_t)(z * BR + row) * SLEN + kt * BC + c4);
        acc = fmaxf(acc, fmaxf(fmaxf(fabsf(v.x), fabsf(v.y)), fmaxf(fabsf(v.z), fabsf(v.w))));
    }
    unsigned long long any = __ballot(acc != 0.f);
    if ((t & 63) == 0) wany[t >> 6] = (any != 0ull) ? 1 : 0;

    // kv tile load (z = bh): 64 keys x 64 d fp32 -> bf16 Tl[key][d]
    const float* src = kv + ((size_t)z * SLEN + kt * BC) * DH;
#pragma unroll
    for (int i = 0; i < 4; ++i) {
        int f = i * 256 + t;
        int key = f >> 4, d4 = (f & 15) * 4;
        float4 v = *(const float4*)(src + (size_t)key * DH + d4);
        bf16x4 b; b[0] = (bf16)v.x; b[1] = (bf16)v.y; b[2] = (bf16)v.z; b[3] = (bf16)v.w;
        *(bf16x4*)&Tl[key * 72 + d4] = b;
    }
    __syncthreads();
    if (t == 0) flags[z * NKT + kt] = wany[0] | wany[1] | wany[2] | wany[3];

    // K image
    bf16* outK = kvK + ((size_t)z * NKT + kt) * IMGE_G;
#pragma unroll
    for (int i = 0; i < 2; ++i) {
        int G = i * 256 + t;
        int c = G >> 6, L = G & 63, rl = L >> 3, p = L & 7;
        int g = (p - rl - 4 * (c & 1)) & 7, key = 8 * c + rl;
        bf16x8 w = *(const bf16x8*)&Tl[key * 72 + g * 8];
        *(bf16x8*)(outK + (size_t)G * 8) = w;
    }
    // V image: rows = d, content = logical keys 8g..8g+7 gathered via phys_key
    bf16* outV = kvT + ((size_t)z * NKT + kt) * IMGE_G;
#pragma unroll
    for (int i = 0; i < 2; ++i) {
        int G = i * 256 + t;
        int c = G >> 6, L = G & 63, dl = L >> 3, p = L & 7;
        int g = (p - dl - 4 * (c & 1)) & 7, d = 8 * c + dl;
        bf16x8 w;
#pragma unroll
        for (int j = 0; j < 8; ++j)
            w[j] = Tl[phys_key(8 * g + j) * 72 + d];
        *(bf16x8*)(outV + (size_t)G * 8) = w;
    }
}

// ---- main fused attention: R6 numerics, 128-key epochs, 8 waves/block ----
__global__ __launch_bounds__(512) void attn_fwd8(
    const float* __restrict__ q, const float* __restrict__ mask,
    const int* __restrict__ flags,
    const bf16* __restrict__ kvK, const bf16* __restrict__ kvT,
    float* __restrict__ out)
{
    __shared__ __align__(16) char smem[2 * BUF2];   // 64 KiB

    const int bh = blockIdx.x;
    const int qt = blockIdx.y;          // 128-row q tile
    const int q0 = qt * 128;
    const int t = threadIdx.x;
    const int wave = t >> 6, lane = t & 63;   // wave in [0,8)
    const int ln16 = lane & 15, quad = lane >> 4;
    const int ln8 = ln16 & 7, hb = ln16 >> 3;

    // Q B-fragments (scale folded): B[k=kc*32+quad*8+j][n=qrow=ln16]
    const float qscale = 0.125f * LOG2E;
    bf16x8 aq[2];
    {
        const float* qrow = q + ((size_t)bh * SLEN + q0 + wave * 16 + ln16) * DH;
#pragma unroll
        for (int kc = 0; kc < 2; ++kc) {
            float4 f0 = *(const float4*)(qrow + kc * 32 + quad * 8);
            float4 f1 = *(const float4*)(qrow + kc * 32 + quad * 8 + 4);
            bf16x8 a;
            a[0] = (bf16)(f0.x * qscale); a[1] = (bf16)(f0.y * qscale);
            a[2] = (bf16)(f0.z * qscale); a[3] = (bf16)(f0.w * qscale);
            a[4] = (bf16)(f1.x * qscale); a[5] = (bf16)(f1.y * qscale);
            a[6] = (bf16)(f1.z * qscale); a[7] = (bf16)(f1.w * qscale);
            aq[kc] = a;
        }
    }

    // flag bitmask for this wave's 64-row flag tile (bit = 64-key tile kt)
    const int fqt = qt * 2 + (wave >> 2);
    unsigned fmask;
    {
        int ld = (lane < 32) ? flags[fqt * NKT + lane] : 0;
        fmask = (unsigned)__ballot(ld != 0);
    }

    // conflict-swizzled read offsets: slot = (quad + kc*4 + ln8 + 4*hb) & 7
    const int kbase0 = hb * CHB_L + ln8 * 128 + (((quad + ln8 + 4 * hb) & 7) << 4);
    const int kbase1 = hb * CHB_L + ln8 * 128 + (((quad + 4 + ln8 + 4 * hb) & 7) << 4);

    floatx4 o[4];
#pragma unroll
    for (int dt = 0; dt < 4; ++dt) o[dt] = (floatx4){0.f, 0.f, 0.f, 0.f};
    float m_run = -3.0e38f, l_run = 0.f;

    const bf16* kvKb = kvK + (size_t)bh * NKT * IMGE_G;
    const bf16* kvTb = kvT + (size_t)bh * NKT * IMGE_G;

    // prologue: stage tiles 0,1 into buffer 0 (each wave: chunk `wave` of 4 images)
    {
        char* B0 = smem;
        gload_lds16(kvKb + (size_t)wave * 512 + lane * 8,           B0 +             wave * CHB_L);
        gload_lds16(kvTb + (size_t)wave * 512 + lane * 8,           B0 + IMGB_L +    wave * CHB_L);
        gload_lds16(kvKb + IMGE_G + (size_t)wave * 512 + lane * 8,  B0 + 2*IMGB_L +  wave * CHB_L);
        gload_lds16(kvTb + IMGE_G + (size_t)wave * 512 + lane * 8,  B0 + 3*IMGB_L +  wave * CHB_L);
    }

    for (int e = 0; e < NEP; ++e) {
        __syncthreads();   // drains vmcnt -> buf[e&1] ready; prev compute done

        if (e + 1 < NEP) {   // prefetch next epoch's 2 tiles into the other buffer
            char* Bn = smem + ((e + 1) & 1) * BUF2;
            const bf16* gK0 = kvKb + (size_t)(2 * e + 2) * IMGE_G;
            const bf16* gV0 = kvTb + (size_t)(2 * e + 2) * IMGE_G;
            gload_lds16(gK0 + (size_t)wave * 512 + lane * 8,          Bn +            wave * CHB_L);
            gload_lds16(gV0 + (size_t)wave * 512 + lane * 8,          Bn + IMGB_L +   wave * CHB_L);
            gload_lds16(gK0 + IMGE_G + (size_t)wave * 512 + lane * 8, Bn + 2*IMGB_L + wave * CHB_L);
            gload_lds16(gV0 + IMGE_G + (size_t)wave * 512 + lane * 8, Bn + 3*IMGB_L + wave * CHB_L);
        }

        const char* B  = smem + (e & 1) * BUF2;
        const char* K0 = B;
        const char* V0 = B + IMGB_L;
        const char* K1 = B + 2 * IMGB_L;
        const char* V1 = B + 3 * IMGB_L;

        // S^T = K * Q^T for both sub-tiles (independent chains)
        floatx4 s0[4], s1[4];
#pragma unroll
        for (int nt = 0; nt < 4; ++nt) {
            bf16x8 a0 = *(const bf16x8*)(K0 + nt * 2048 + kbase0);
            bf16x8 a1 = *(const bf16x8*)(K0 + nt * 2048 + kbase1);
            floatx4 acc = (floatx4){0.f, 0.f, 0.f, 0.f};
            acc = __builtin_amdgcn_mfma_f32_16x16x32_bf16(a0, aq[0], acc, 0, 0, 0);
            acc = __builtin_amdgcn_mfma_f32_16x16x32_bf16(a1, aq[1], acc, 0, 0, 0);
            s0[nt] = acc;
        }
#pragma unroll
        for (int nt = 0; nt < 4; ++nt) {
            bf16x8 a0 = *(const bf16x8*)(K1 + nt * 2048 + kbase0);
            bf16x8 a1 = *(const bf16x8*)(K1 + nt * 2048 + kbase1);
            floatx4 acc = (floatx4){0.f, 0.f, 0.f, 0.f};
            acc = __builtin_amdgcn_mfma_f32_16x16x32_bf16(a0, aq[0], acc, 0, 0, 0);
            acc = __builtin_amdgcn_mfma_f32_16x16x32_bf16(a1, aq[1], acc, 0, 0, 0);
            s1[nt] = acc;
        }

        // mask add per 64-key sub-tile (usually skipped)
        if (fmask & (1u << (2 * e))) {
            const float* mrow = mask + (size_t)(q0 + wave * 16 + ln16) * SLEN + (2 * e) * BC;
#pragma unroll
            for (int nt = 0; nt < 4; ++nt) {
                float4 mv = *(const float4*)(mrow + 16 * nt + quad * 4);
                s0[nt][0] += mv.x * LOG2E; s0[nt][1] += mv.y * LOG2E;
                s0[nt][2] += mv.z * LOG2E; s0[nt][3] += mv.w * LOG2E;
            }
        }
        if (fmask & (1u << (2 * e + 1))) {
            const float* mrow = mask + (size_t)(q0 + wave * 16 + ln16) * SLEN + (2 * e + 1) * BC;
#pragma unroll
            for (int nt = 0; nt < 4; ++nt) {
                float4 mv = *(const float4*)(mrow + 16 * nt + quad * 4);
                s1[nt][0] += mv.x * LOG2E; s1[nt][1] += mv.y * LOG2E;
                s1[nt][2] += mv.z * LOG2E; s1[nt][3] += mv.w * LOG2E;
            }
        }

        // online softmax over 128 keys: one q-row per lane (row = ln16)
        float tm0 = s0[0][0], tm1 = s1[0][0];
#pragma unroll
        for (int nt = 0; nt < 4; ++nt)
#pragma unroll
            for (int r = 0; r < 4; ++r) {
                tm0 = fmaxf(tm0, s0[nt][r]);
                tm1 = fmaxf(tm1, s1[nt][r]);
            }
        float tmax = fmaxf(tm0, tm1);
        tmax = fmaxf(tmax, __shfl_xor(tmax, 16));
        tmax = fmaxf(tmax, __shfl_xor(tmax, 32));
        float mnew = fmaxf(m_run, tmax);
        unsigned long long grew = __ballot(mnew > m_run);
        float alpha = exp2f(m_run - mnew);
        m_run = mnew;

        float rs = 0.f;
        bf16x8 pf00, pf01, pf10, pf11;
#pragma unroll
        for (int r = 0; r < 4; ++r) {
            float a0 = exp2f(s0[0][r] - mnew);
            float a1 = exp2f(s0[1][r] - mnew);
            float a2 = exp2f(s0[2][r] - mnew);
            float a3 = exp2f(s0[3][r] - mnew);
            float b0 = exp2f(s1[0][r] - mnew);
            float b1 = exp2f(s1[1][r] - mnew);
            float b2 = exp2f(s1[2][r] - mnew);
            float b3 = exp2f(s1[3][r] - mnew);
            rs += ((a0 + a1) + (a2 + a3)) + ((b0 + b1) + (b2 + b3));
            pf00[r] = (bf16)a0; pf00[4 + r] = (bf16)a1;
            pf01[r] = (bf16)a2; pf01[4 + r] = (bf16)a3;
            pf10[r] = (bf16)b0; pf10[4 + r] = (bf16)b1;
            pf11[r] = (bf16)b2; pf11[4 + r] = (bf16)b3;
        }
        rs += __shfl_xor(rs, 16);
        rs += __shfl_xor(rs, 32);

        if (grew) {
            l_run = l_run * alpha + rs;
            float a0 = __shfl(alpha, quad * 4 + 0);
            float a1 = __shfl(alpha, quad * 4 + 1);
            float a2 = __shfl(alpha, quad * 4 + 2);
            float a3 = __shfl(alpha, quad * 4 + 3);
#pragma unroll
            for (int dt = 0; dt < 4; ++dt) {
                o[dt][0] *= a0; o[dt][1] *= a1; o[dt][2] *= a2; o[dt][3] *= a3;
            }
        } else {
            l_run += rs;
        }

        // O += P V for both sub-tiles
#pragma unroll
        for (int dt = 0; dt < 4; ++dt) {
            bf16x8 v0 = *(const bf16x8*)(V0 + dt * 2048 + kbase0);
            bf16x8 v1 = *(const bf16x8*)(V0 + dt * 2048 + kbase1);
            o[dt] = __builtin_amdgcn_mfma_f32_16x16x32_bf16(pf00, v0, o[dt], 0, 0, 0);
            o[dt] = __builtin_amdgcn_mfma_f32_16x16x32_bf16(pf01, v1, o[dt], 0, 0, 0);
        }
#pragma unroll
        for (int dt = 0; dt < 4; ++dt) {
            bf16x8 v0 = *(const bf16x8*)(V1 + dt * 2048 + kbase0);
            bf16x8 v1 = *(const bf16x8*)(V1 + dt * 2048 + kbase1);
            o[dt] = __builtin_amdgcn_mfma_f32_16x16x32_bf16(pf10, v0, o[dt], 0, 0, 0);
            o[dt] = __builtin_amdgcn_mfma_f32_16x16x32_bf16(pf11, v1, o[dt], 0, 0, 0);
        }
    }

    // epilogue: O rows = quad*4+r, cols = ln16+16dt; l lives at lane quad*4+r
    float l0 = __shfl(l_run, quad * 4 + 0);
    float l1 = __shfl(l_run, quad * 4 + 1);
    float l2 = __shfl(l_run, quad * 4 + 2);
    float l3 = __shfl(l_run, quad * 4 + 3);
    float i0 = 1.f / l0, i1 = 1.f / l1, i2 = 1.f / l2, i3 = 1.f / l3;
    float* ob = out + ((size_t)bh * SLEN + q0 + wave * 16) * DH;
#pragma unroll
    for (int dt = 0; dt < 4; ++dt) {
        int col = ln16 + 16 * dt;
        ob[(quad * 4 + 0) * DH + col] = o[dt][0] * i0;
        ob[(quad * 4 + 1) * DH + col] = o[dt][1] * i1;
        ob[(quad * 4 + 2) * DH + col] = o[dt][2] * i2;
        ob[(quad * 4 + 3) * DH + col] = o[dt][3] * i3;
    }
}

// ---- legacy fallback (round-1 kernel) if ws is too small for the prepass ----
#define LDT 72
__global__ __launch_bounds__(256) void attn_mask_flags(
    const float* __restrict__ mask, int* __restrict__ flags)
{
    const int kt = blockIdx.x, qt = blockIdx.y;
    const int t = threadIdx.x;
    float acc = 0.f;
#pragma unroll
    for (int i = 0; i < 4; ++i) {
        int f = i * 256 + t;
        int row = f >> 4, c4 = (f & 15) * 4;
        const float4 v = *(const float4*)(mask + (size_t)(qt * BR + row) * SLEN + kt * BC + c4);
        acc = fmaxf(acc, fmaxf(fmaxf(fabsf(v.x), fabsf(v.y)), fmaxf(fabsf(v.z), fabsf(v.w))));
    }
    unsigned long long any = __ballot(acc != 0.f);
    __shared__ int wany[4];
    if ((t & 63) == 0) wany[t >> 6] = (any != 0ull) ? 1 : 0;
    __syncthreads();
    if (t == 0) flags[qt * NKT + kt] = wany[0] | wany[1] | wany[2] | wany[3];
}

__global__ __launch_bounds__(256) void attn_fwd(
    const float* __restrict__ q, const float* __restrict__ kv,
    const float* __restrict__ mask, const int* __restrict__ flags,
    float* __restrict__ out)
{
    __shared__ __align__(16) bf16 Kl[BC * LDT];
    __shared__ __align__(16) bf16 Vt[DH * LDT];
    __shared__ __align__(16) bf16 Pl[BR * LDT];

    const int qt = blockIdx.x;
    const int bh = blockIdx.y;
    const int q0 = qt * BR;
    const int t = threadIdx.x;
    const int wave = t >> 6, lane = t & 63;
    const int ln16 = lane & 15, quad = lane >> 4;

    const float qscale = 0.125f * LOG2E;
    bf16x8 aq[2];
    {
        const float* qrow = q + ((size_t)bh * SLEN + q0 + wave * 16 + ln16) * DH;
#pragma unroll
        for (int kc = 0; kc < 2; ++kc) {
            float4 f0 = *(const float4*)(qrow + kc * 32 + quad * 8);
            float4 f1 = *(const float4*)(qrow + kc * 32 + quad * 8 + 4);
            bf16x8 a;
            a[0] = (bf16)(f0.x * qscale); a[1] = (bf16)(f0.y * qscale);
            a[2] = (bf16)(f0.z * qscale); a[3] = (bf16)(f0.w * qscale);
            a[4] = (bf16)(f1.x * qscale); a[5] = (bf16)(f1.y * qscale);
            a[6] = (bf16)(f1.z * qscale); a[7] = (bf16)(f1.w * qscale);
            aq[kc] = a;
        }
    }

    floatx4 o[4];
#pragma unroll
    for (int dt = 0; dt < 4; ++dt) o[dt] = (floatx4){0.f, 0.f, 0.f, 0.f};
    float m_run[4], l_run[4];
#pragma unroll
    for (int r = 0; r < 4; ++r) { m_run[r] = -3.0e38f; l_run[r] = 0.f; }

    const float* kvb = kv + (size_t)bh * SLEN * DH;

    for (int kt = 0; kt < NKT; ++kt) {
        float4 st[4];
        const float* kvt = kvb + (size_t)kt * BC * DH;
#pragma unroll
        for (int i = 0; i < 4; ++i) {
            int f = i * 256 + t;
            st[i] = *(const float4*)(kvt + (size_t)f * 4);
        }
        __syncthreads();
#pragma unroll
        for (int i = 0; i < 4; ++i) {
            int f = i * 256 + t;
            int key = f >> 4, d4 = (f & 15) * 4;
            bf16 b0 = (bf16)st[i].x, b1 = (bf16)st[i].y, b2 = (bf16)st[i].z, b3 = (bf16)st[i].w;
            *(bf16x4*)&Kl[key * LDT + d4] = (bf16x4){b0, b1, b2, b3};
            Vt[(d4 + 0) * LDT + key] = b0;
            Vt[(d4 + 1) * LDT + key] = b1;
            Vt[(d4 + 2) * LDT + key] = b2;
            Vt[(d4 + 3) * LDT + key] = b3;
        }
        __syncthreads();

        floatx4 s[4];
#pragma unroll
        for (int nt = 0; nt < 4; ++nt) {
            s[nt] = (floatx4){0.f, 0.f, 0.f, 0.f};
#pragma unroll
            for (int kc = 0; kc < 2; ++kc) {
                bf16x8 bk = *(const bf16x8*)&Kl[(ln16 + 16 * nt) * LDT + kc * 32 + quad * 8];
                s[nt] = __builtin_amdgcn_mfma_f32_16x16x32_bf16(aq[kc], bk, s[nt], 0, 0, 0);
            }
        }

        if (!flags || flags[qt * NKT + kt]) {
            const float* mrow = mask + (size_t)(q0 + quad * 4) * SLEN + kt * BC + ln16;
#pragma unroll
            for (int r = 0; r < 4; ++r)
#pragma unroll
                for (int nt = 0; nt < 4; ++nt)
                    s[nt][r] += mrow[(size_t)r * SLEN + nt * 16] * LOG2E;
        }

#pragma unroll
        for (int r = 0; r < 4; ++r) {
            float mx = fmaxf(fmaxf(s[0][r], s[1][r]), fmaxf(s[2][r], s[3][r]));
            mx = fmaxf(mx, __shfl_xor(mx, 1));
            mx = fmaxf(mx, __shfl_xor(mx, 2));
            mx = fmaxf(mx, __shfl_xor(mx, 4));
            mx = fmaxf(mx, __shfl_xor(mx, 8));
            float mnew = fmaxf(m_run[r], mx);
            float alpha = exp2f(m_run[r] - mnew);
            m_run[r] = mnew;
            float rs = 0.f;
#pragma unroll
            for (int nt = 0; nt < 4; ++nt) {
                float p = exp2f(s[nt][r] - mnew);
                s[nt][r] = p;
                rs += p;
            }
            rs += __shfl_xor(rs, 1);
            rs += __shfl_xor(rs, 2);
            rs += __shfl_xor(rs, 4);
            rs += __shfl_xor(rs, 8);
            l_run[r] = l_run[r] * alpha + rs;
#pragma unroll
            for (int dt = 0; dt < 4; ++dt) o[dt][r] *= alpha;
        }

#pragma unroll
        for (int nt = 0; nt < 4; ++nt)
#pragma unroll
            for (int r = 0; r < 4; ++r)
                Pl[(wave * 16 + quad * 4 + r) * LDT + ln16 + 16 * nt] = (bf16)s[nt][r];

#pragma unroll
        for (int kc2 = 0; kc2 < 2; ++kc2) {
            bf16x8 pfr = *(const bf16x8*)&Pl[(wave * 16 + ln16) * LDT + kc2 * 32 + quad * 8];
#pragma unroll
            for (int dt = 0; dt < 4; ++dt) {
                bf16x8 vfr = *(const bf16x8*)&Vt[(ln16 + 16 * dt) * LDT + kc2 * 32 + quad * 8];
                o[dt] = __builtin_amdgcn_mfma_f32_16x16x32_bf16(pfr, vfr, o[dt], 0, 0, 0);
            }
        }
    }

#pragma unroll
    for (int r = 0; r < 4; ++r) {
        float inv = 1.0f / l_run[r];
        int qrow = q0 + wave * 16 + quad * 4 + r;
        float* orow = out + ((size_t)bh * SLEN + qrow) * DH;
#pragma unroll
        for (int dt = 0; dt < 4; ++dt)
            orow[ln16 + 16 * dt] = o[dt][r] * inv;
    }
}

extern "C" void kernel_launch(void* const* d_in, const int* in_sizes, int n_in,
                              void* d_out, int out_size, void* d_ws, size_t ws_size,
                              hipStream_t stream)
{
    const float* q    = (const float*)d_in[0];
    const float* kv   = (const float*)d_in[1];
    const float* mask = (const float*)d_in[2];
    float* out = (float*)d_out;

    const size_t kvKoff = 4096;                                   // flags: 32*32*4
    const size_t kvToff = kvKoff + (size_t)BH_N * NKT * IMGE_G * 2;
    const size_t need   = kvToff + (size_t)BH_N * NKT * IMGE_G * 2;

    if (ws_size >= need) {
        int*  flags = (int*)d_ws;
        bf16* kvK   = (bf16*)((char*)d_ws + kvKoff);
        bf16* kvT   = (bf16*)((char*)d_ws + kvToff);
        kv_prep<<<dim3(NKT, BH_N), 256, 0, stream>>>(kv, mask, kvK, kvT, flags);
        attn_fwd8<<<dim3(BH_N, SLEN / 128), 512, 0, stream>>>(q, mask, flags, kvK, kvT, out);
    } else {
        int* flags = nullptr;
        if (ws_size >= (size_t)NQT * NKT * sizeof(int)) {
            flags = (int*)d_ws;
            attn_mask_flags<<<dim3(NKT, NQT), 256, 0, stream>>>(mask, flags);
        }
        attn_fwd<<<dim3(NQT, BH_N), 256, 0, stream>>>(q, kv, mask, flags, out);
    }
}